// Round 1
// baseline (1600.314 us; speedup 1.0000x reference)
//
#include <hip/hip_runtime.h>

#define NB 4
#define NL 2048
#define ND 512
#define NH 8
#define NDK 64
#define NTOK (NB * NL)  // 8192

constexpr float TEMP_INV = 0.125f;  // 1/sqrt(DK)=1/8
constexpr float LN_EPS = 1e-5f;

// ---------------------------------------------------------------------------
// GEMM (NT): Y[n][o] = sum_c X[n][c] * W[o][c] + bias[o]
// M = gridDim.x*64 (8192), N = gridDim.y*64 (512), K = 512.
// 64x64 tile, 256 threads, 4x4 per thread, BK=16.
// ---------------------------------------------------------------------------
__global__ __launch_bounds__(256) void gemm_nt(const float* __restrict__ X,
                                               const float* __restrict__ W,
                                               const float* __restrict__ bias,
                                               float* __restrict__ Y) {
  __shared__ float As[16][64];  // [k][m]
  __shared__ float Bs[16][64];  // [k][n]
  const int tid = threadIdx.x;
  const int tx = tid & 15, ty = tid >> 4;
  const int m0 = blockIdx.x * 64, n0 = blockIdx.y * 64;
  const int lrow = tid >> 2, lseg = tid & 3;  // 64 rows x 4 segments of 4
  float acc[4][4] = {};
  for (int k0 = 0; k0 < 512; k0 += 16) {
    const float4 xa = *(const float4*)&X[(size_t)(m0 + lrow) * ND + k0 + lseg * 4];
    const float4 wb = *(const float4*)&W[(size_t)(n0 + lrow) * ND + k0 + lseg * 4];
    __syncthreads();  // previous iteration's LDS reads done
    As[lseg * 4 + 0][lrow] = xa.x;
    As[lseg * 4 + 1][lrow] = xa.y;
    As[lseg * 4 + 2][lrow] = xa.z;
    As[lseg * 4 + 3][lrow] = xa.w;
    Bs[lseg * 4 + 0][lrow] = wb.x;
    Bs[lseg * 4 + 1][lrow] = wb.y;
    Bs[lseg * 4 + 2][lrow] = wb.z;
    Bs[lseg * 4 + 3][lrow] = wb.w;
    __syncthreads();
#pragma unroll
    for (int kk = 0; kk < 16; ++kk) {
      float av[4], bv[4];
      {
        const float4 t = *(const float4*)&As[kk][ty * 4];
        av[0] = t.x; av[1] = t.y; av[2] = t.z; av[3] = t.w;
      }
      {
        const float4 t = *(const float4*)&Bs[kk][tx * 4];
        bv[0] = t.x; bv[1] = t.y; bv[2] = t.z; bv[3] = t.w;
      }
#pragma unroll
      for (int i = 0; i < 4; ++i)
#pragma unroll
        for (int j = 0; j < 4; ++j) acc[i][j] += av[i] * bv[j];
    }
  }
  const int oc = n0 + tx * 4;
#pragma unroll
  for (int i = 0; i < 4; ++i) {
    float4 o;
    o.x = acc[i][0] + bias[oc + 0];
    o.y = acc[i][1] + bias[oc + 1];
    o.z = acc[i][2] + bias[oc + 2];
    o.w = acc[i][3] + bias[oc + 3];
    *(float4*)&Y[(size_t)(m0 + ty * 4 + i) * ND + oc] = o;
  }
}

// ---------------------------------------------------------------------------
// Fused attention: per (b, h, 64-query tile).
// Pass 1: scores = (Qh/8)·Kh^T, masked, accumulate rowsum of exp(s).
// Pass 2: recompute scores, p = exp(s)/rowsum -> write attn (d_out), stage P
//         in LDS, accumulate O = P·V in registers -> write attn_out (ws).
// LDS: 4 x 64x64 f32 = 64 KiB exactly; red/invs alias the (pass-2-only) Ps.
// ---------------------------------------------------------------------------
__global__ __launch_bounds__(256) void attn_fused(const float* __restrict__ qp,
                                                  const float* __restrict__ kp,
                                                  const float* __restrict__ vp,
                                                  const int* __restrict__ mask,
                                                  float* __restrict__ attn,
                                                  float* __restrict__ ao) {
  const int b = blockIdx.z, h = blockIdx.y, q0 = blockIdx.x * 64;
  __shared__ float Qt[64][64];  // [d][q], pre-scaled by 1/8
  __shared__ float Kt[64][64];  // [d][k]
  __shared__ float Vs[64][64];  // [k][d]
  __shared__ float Ps[64][64];  // [q][k] (pass 2); first 1088 floats alias red/invs
  float* red = &Ps[0][0];       // [16][64]: red[t*64+q]
  float* invs = &Ps[16][0];     // [64]
  const int tid = threadIdx.x;
  const int tx = tid & 15, ty = tid >> 4;
  const int lrow = tid >> 2, lseg = tid & 3;

  // load Q tile transposed + scaled
  {
    const float* src = qp + (size_t)(b * NL + q0 + lrow) * ND + h * 64 + lseg * 16;
#pragma unroll
    for (int s = 0; s < 4; ++s) {
      const float4 t = *(const float4*)(src + s * 4);
      const int d = lseg * 16 + s * 4;
      Qt[d + 0][lrow] = t.x * TEMP_INV;
      Qt[d + 1][lrow] = t.y * TEMP_INV;
      Qt[d + 2][lrow] = t.z * TEMP_INV;
      Qt[d + 3][lrow] = t.w * TEMP_INV;
    }
  }

  float rsum[4] = {0.f, 0.f, 0.f, 0.f};
  // ----- PASS 1 -----
  for (int kt = 0; kt < 32; ++kt) {
    float4 kv[4];
    const float* ksrc = kp + (size_t)(b * NL + kt * 64 + lrow) * ND + h * 64 + lseg * 16;
#pragma unroll
    for (int s = 0; s < 4; ++s) kv[s] = *(const float4*)(ksrc + s * 4);
    __syncthreads();
#pragma unroll
    for (int s = 0; s < 4; ++s) {
      const int d = lseg * 16 + s * 4;
      Kt[d + 0][lrow] = kv[s].x;
      Kt[d + 1][lrow] = kv[s].y;
      Kt[d + 2][lrow] = kv[s].z;
      Kt[d + 3][lrow] = kv[s].w;
    }
    __syncthreads();
    float sacc[4][4] = {};
#pragma unroll 4
    for (int d = 0; d < 64; ++d) {
      float qa[4], kb[4];
      {
        const float4 t = *(const float4*)&Qt[d][ty * 4];
        qa[0] = t.x; qa[1] = t.y; qa[2] = t.z; qa[3] = t.w;
      }
      {
        const float4 t = *(const float4*)&Kt[d][tx * 4];
        kb[0] = t.x; kb[1] = t.y; kb[2] = t.z; kb[3] = t.w;
      }
#pragma unroll
      for (int i = 0; i < 4; ++i)
#pragma unroll
        for (int j = 0; j < 4; ++j) sacc[i][j] += qa[i] * kb[j];
    }
#pragma unroll
    for (int i = 0; i < 4; ++i) {
      const int4 m4 = *(const int4*)&mask[((size_t)b * NL + q0 + ty * 4 + i) * NL + kt * 64 + tx * 4];
      rsum[i] += (m4.x == 1) ? 0.f : __expf(sacc[i][0]);
      rsum[i] += (m4.y == 1) ? 0.f : __expf(sacc[i][1]);
      rsum[i] += (m4.z == 1) ? 0.f : __expf(sacc[i][2]);
      rsum[i] += (m4.w == 1) ? 0.f : __expf(sacc[i][3]);
    }
  }
  // reduce row sums across the 16 tx threads of each q row
  __syncthreads();
#pragma unroll
  for (int i = 0; i < 4; ++i) red[tx * 64 + ty * 4 + i] = rsum[i];
  __syncthreads();
  if (tid < 64) {
    float s = 0.f;
#pragma unroll
    for (int t = 0; t < 16; ++t) s += red[t * 64 + tid];
    invs[tid] = 1.0f / s;
  }
  __syncthreads();
  float inv4[4];
#pragma unroll
  for (int i = 0; i < 4; ++i) inv4[i] = invs[ty * 4 + i];

  // ----- PASS 2 -----
  float oacc[4][4] = {};
  for (int kt = 0; kt < 32; ++kt) {
    float4 kv[4], vv[4];
    const float* ksrc = kp + (size_t)(b * NL + kt * 64 + lrow) * ND + h * 64 + lseg * 16;
    const float* vsrc = vp + (size_t)(b * NL + kt * 64 + lrow) * ND + h * 64 + lseg * 16;
#pragma unroll
    for (int s = 0; s < 4; ++s) kv[s] = *(const float4*)(ksrc + s * 4);
#pragma unroll
    for (int s = 0; s < 4; ++s) vv[s] = *(const float4*)(vsrc + s * 4);
    __syncthreads();  // prior iter PV reads (and inv4 reads) done
#pragma unroll
    for (int s = 0; s < 4; ++s) {
      const int d = lseg * 16 + s * 4;
      Kt[d + 0][lrow] = kv[s].x;
      Kt[d + 1][lrow] = kv[s].y;
      Kt[d + 2][lrow] = kv[s].z;
      Kt[d + 3][lrow] = kv[s].w;
      *(float4*)&Vs[lrow][d] = vv[s];
    }
    __syncthreads();
    float sacc[4][4] = {};
#pragma unroll 4
    for (int d = 0; d < 64; ++d) {
      float qa[4], kb[4];
      {
        const float4 t = *(const float4*)&Qt[d][ty * 4];
        qa[0] = t.x; qa[1] = t.y; qa[2] = t.z; qa[3] = t.w;
      }
      {
        const float4 t = *(const float4*)&Kt[d][tx * 4];
        kb[0] = t.x; kb[1] = t.y; kb[2] = t.z; kb[3] = t.w;
      }
#pragma unroll
      for (int i = 0; i < 4; ++i)
#pragma unroll
        for (int j = 0; j < 4; ++j) sacc[i][j] += qa[i] * kb[j];
    }
#pragma unroll
    for (int i = 0; i < 4; ++i) {
      const int q = ty * 4 + i;
      const int4 m4 = *(const int4*)&mask[((size_t)b * NL + q0 + q) * NL + kt * 64 + tx * 4];
      float4 pv;
      pv.x = (m4.x == 1) ? 0.f : __expf(sacc[i][0]) * inv4[i];
      pv.y = (m4.y == 1) ? 0.f : __expf(sacc[i][1]) * inv4[i];
      pv.z = (m4.z == 1) ? 0.f : __expf(sacc[i][2]) * inv4[i];
      pv.w = (m4.w == 1) ? 0.f : __expf(sacc[i][3]) * inv4[i];
      *(float4*)&attn[((size_t)(b * NH + h) * NL + q0 + q) * NL + kt * 64 + tx * 4] = pv;
      *(float4*)&Ps[q][tx * 4] = pv;
    }
    __syncthreads();
    // O += P(64x64) * V(64x64); thread -> (q=ty*4.., d=tx*4..)
#pragma unroll 2
    for (int kk = 0; kk < 64; kk += 4) {
      float pa[4][4], vb[4][4];
#pragma unroll
      for (int i = 0; i < 4; ++i) {
        const float4 t = *(const float4*)&Ps[ty * 4 + i][kk];
        pa[i][0] = t.x; pa[i][1] = t.y; pa[i][2] = t.z; pa[i][3] = t.w;
      }
#pragma unroll
      for (int u = 0; u < 4; ++u) {
        const float4 t = *(const float4*)&Vs[kk + u][tx * 4];
        vb[u][0] = t.x; vb[u][1] = t.y; vb[u][2] = t.z; vb[u][3] = t.w;
      }
#pragma unroll
      for (int i = 0; i < 4; ++i)
#pragma unroll
        for (int j = 0; j < 4; ++j)
#pragma unroll
          for (int u = 0; u < 4; ++u) oacc[i][j] += pa[i][u] * vb[u][j];
    }
  }
  // write attn-out tile (natural (b,h,q,d) layout)
#pragma unroll
  for (int i = 0; i < 4; ++i) {
    float4 o;
    o.x = oacc[i][0]; o.y = oacc[i][1]; o.z = oacc[i][2]; o.w = oacc[i][3];
    *(float4*)&ao[((size_t)(b * NH + h) * NL + q0 + ty * 4 + i) * 64 + tx * 4] = o;
  }
}

// ---------------------------------------------------------------------------
// fc with the faithful buffer-scramble gather on A + bias + residual.
// Xout[n][o] = sum_c scr(n,c) * W[o][c] + bias[o] + resid[n][o]
// scr(n,c) = AO[(h2*4+b2)*2048*64 + q2*64 + d2],
//   h2=2*b_out+(l_out>>10), q2=((l_out&1023)<<1)|((c>>8)&1), b2=(c>>6)&3, d2=c&63
// ---------------------------------------------------------------------------
__global__ __launch_bounds__(256) void fc_gather(const float* __restrict__ AO,
                                                 const float* __restrict__ W,
                                                 const float* __restrict__ bias,
                                                 const float* __restrict__ resid,
                                                 float* __restrict__ Xout) {
  __shared__ float As[16][64];
  __shared__ float Bs[16][64];
  const int tid = threadIdx.x;
  const int tx = tid & 15, ty = tid >> 4;
  const int m0 = blockIdx.x * 64, n0 = blockIdx.y * 64;
  const int lrow = tid >> 2, lseg = tid & 3;
  const int n = m0 + lrow;
  const int b_out = n >> 11;
  const int l_out = n & 2047;
  const int h2 = b_out * 2 + (l_out >> 10);
  const int q2base = (l_out & 1023) << 1;
  float acc[4][4] = {};
  for (int k0 = 0; k0 < 512; k0 += 16) {
    const int c = k0 + lseg * 4;
    const int q2 = q2base | ((c >> 8) & 1);
    const int b2 = (c >> 6) & 3;
    const int d2 = c & 63;
    const float4 xa = *(const float4*)&AO[((size_t)(h2 * 4 + b2) * NL + q2) * 64 + d2];
    const float4 wb = *(const float4*)&W[(size_t)(n0 + lrow) * ND + c];
    __syncthreads();
    As[lseg * 4 + 0][lrow] = xa.x;
    As[lseg * 4 + 1][lrow] = xa.y;
    As[lseg * 4 + 2][lrow] = xa.z;
    As[lseg * 4 + 3][lrow] = xa.w;
    Bs[lseg * 4 + 0][lrow] = wb.x;
    Bs[lseg * 4 + 1][lrow] = wb.y;
    Bs[lseg * 4 + 2][lrow] = wb.z;
    Bs[lseg * 4 + 3][lrow] = wb.w;
    __syncthreads();
#pragma unroll
    for (int kk = 0; kk < 16; ++kk) {
      float av[4], bv[4];
      {
        const float4 t = *(const float4*)&As[kk][ty * 4];
        av[0] = t.x; av[1] = t.y; av[2] = t.z; av[3] = t.w;
      }
      {
        const float4 t = *(const float4*)&Bs[kk][tx * 4];
        bv[0] = t.x; bv[1] = t.y; bv[2] = t.z; bv[3] = t.w;
      }
#pragma unroll
      for (int i = 0; i < 4; ++i)
#pragma unroll
        for (int j = 0; j < 4; ++j) acc[i][j] += av[i] * bv[j];
    }
  }
  const int oc = n0 + tx * 4;
#pragma unroll
  for (int i = 0; i < 4; ++i) {
    const float4 r = *(const float4*)&resid[(size_t)(m0 + ty * 4 + i) * ND + oc];
    float4 o;
    o.x = acc[i][0] + bias[oc + 0] + r.x;
    o.y = acc[i][1] + bias[oc + 1] + r.y;
    o.z = acc[i][2] + bias[oc + 2] + r.z;
    o.w = acc[i][3] + bias[oc + 3] + r.w;
    *(float4*)&Xout[(size_t)(m0 + ty * 4 + i) * ND + oc] = o;
  }
}

// ---------------------------------------------------------------------------
// LayerNorm over last dim (512), one wave per token.
// ---------------------------------------------------------------------------
__global__ __launch_bounds__(64) void layernorm_k(const float* __restrict__ x,
                                                  const float* __restrict__ g,
                                                  const float* __restrict__ bta,
                                                  float* __restrict__ y) {
  const int n = blockIdx.x;
  const int lane = threadIdx.x;
  const float* row = x + (size_t)n * ND;
  const float4 a = *(const float4*)&row[lane * 8];
  const float4 c = *(const float4*)&row[lane * 8 + 4];
  float s = a.x + a.y + a.z + a.w + c.x + c.y + c.z + c.w;
  float sq = a.x * a.x + a.y * a.y + a.z * a.z + a.w * a.w +
             c.x * c.x + c.y * c.y + c.z * c.z + c.w * c.w;
#pragma unroll
  for (int off = 32; off; off >>= 1) {
    s += __shfl_down(s, off);
    sq += __shfl_down(sq, off);
  }
  s = __shfl(s, 0);
  sq = __shfl(sq, 0);
  const float mu = s * (1.f / 512.f);
  const float var = sq * (1.f / 512.f) - mu * mu;
  const float rstd = rsqrtf(var + LN_EPS);
  float* yo = y + (size_t)n * ND;
  const int c0 = lane * 8;
  float4 o1, o2;
  o1.x = (a.x - mu) * rstd * g[c0 + 0] + bta[c0 + 0];
  o1.y = (a.y - mu) * rstd * g[c0 + 1] + bta[c0 + 1];
  o1.z = (a.z - mu) * rstd * g[c0 + 2] + bta[c0 + 2];
  o1.w = (a.w - mu) * rstd * g[c0 + 3] + bta[c0 + 3];
  o2.x = (c.x - mu) * rstd * g[c0 + 4] + bta[c0 + 4];
  o2.y = (c.y - mu) * rstd * g[c0 + 5] + bta[c0 + 5];
  o2.z = (c.z - mu) * rstd * g[c0 + 6] + bta[c0 + 6];
  o2.w = (c.w - mu) * rstd * g[c0 + 7] + bta[c0 + 7];
  *(float4*)&yo[c0] = o1;
  *(float4*)&yo[c0 + 4] = o2;
}

extern "C" void kernel_launch(void* const* d_in, const int* in_sizes, int n_in,
                              void* d_out, int out_size, void* d_ws, size_t ws_size,
                              hipStream_t stream) {
  const float* q = (const float*)d_in[0];
  const float* k = (const float*)d_in[1];
  const float* v = (const float*)d_in[2];
  const int* mask = (const int*)d_in[3];
  const float* wq_w = (const float*)d_in[4];
  const float* wq_b = (const float*)d_in[5];
  const float* wv_w = (const float*)d_in[6];
  const float* wv_b = (const float*)d_in[7];
  const float* fc_w = (const float*)d_in[8];
  const float* fc_b = (const float*)d_in[9];
  const float* ln_g = (const float*)d_in[10];
  const float* ln_b = (const float*)d_in[11];

  float* y = (float*)d_out;
  float* attn = y + (size_t)NTOK * ND;  // second output, (B,H,L,L)

  float* ws = (float*)d_ws;
  const size_t SZ = (size_t)NTOK * ND;  // 4,194,304 floats
  float* qp = ws;            // projected q, (n, 512)
  float* kp = qp + SZ;       // projected k (with Wq — faithful bug)
  float* vp = kp + SZ;       // projected v
  float* ao = vp + SZ;       // attention out, (b,h,q,d)
  float* xx = ao + SZ;       // fc out + residual

  const dim3 gproj(NTOK / 64, ND / 64);  // 128 x 8
  gemm_nt<<<gproj, 256, 0, stream>>>(q, wq_w, wq_b, qp);
  gemm_nt<<<gproj, 256, 0, stream>>>(k, wq_w, wq_b, kp);
  gemm_nt<<<gproj, 256, 0, stream>>>(v, wv_w, wv_b, vp);
  attn_fused<<<dim3(NL / 64, NH, NB), 256, 0, stream>>>(qp, kp, vp, mask, attn, ao);
  fc_gather<<<gproj, 256, 0, stream>>>(ao, fc_w, fc_b, q, xx);
  layernorm_k<<<NTOK, 64, 0, stream>>>(xx, ln_g, ln_b, y);
}

// Round 2
// 997.108 us; speedup vs baseline: 1.6050x; 1.6050x over previous
//
#include <hip/hip_runtime.h>

#define NB 4
#define NL 2048
#define ND 512
#define NH 8
#define NTOK (NB * NL)  // 8192

constexpr float LN_EPS = 1e-5f;

typedef __attribute__((ext_vector_type(8))) short bf16x8;
typedef __attribute__((ext_vector_type(4))) float f32x4;

static __device__ __forceinline__ unsigned short f2bf(float f) {
  unsigned u = __builtin_bit_cast(unsigned, f);
  unsigned r = (u + 0x7fffu + ((u >> 16) & 1u)) >> 16;
  return (unsigned short)r;
}

// ---------------------------------------------------------------------------
// GEMM (NT) f32 core: acc = X[n][c]*W[o][c]. Epilogue variants below.
// 64x64 tile, 256 threads, 4x4 per thread, BK=16.
// ---------------------------------------------------------------------------
#define GEMM_CORE(X, W)                                                        \
  __shared__ float As[16][64];                                                 \
  __shared__ float Bs[16][64];                                                 \
  const int tid = threadIdx.x;                                                 \
  const int tx = tid & 15, ty = tid >> 4;                                      \
  const int m0 = blockIdx.x * 64, n0 = blockIdx.y * 64;                        \
  const int lrow = tid >> 2, lseg = tid & 3;                                   \
  float acc[4][4] = {};                                                        \
  for (int k0 = 0; k0 < 512; k0 += 16) {                                       \
    const float4 xa = *(const float4*)&X[(size_t)(m0 + lrow) * ND + k0 + lseg * 4]; \
    const float4 wb = *(const float4*)&W[(size_t)(n0 + lrow) * ND + k0 + lseg * 4]; \
    __syncthreads();                                                           \
    As[lseg * 4 + 0][lrow] = xa.x;                                             \
    As[lseg * 4 + 1][lrow] = xa.y;                                             \
    As[lseg * 4 + 2][lrow] = xa.z;                                             \
    As[lseg * 4 + 3][lrow] = xa.w;                                             \
    Bs[lseg * 4 + 0][lrow] = wb.x;                                             \
    Bs[lseg * 4 + 1][lrow] = wb.y;                                             \
    Bs[lseg * 4 + 2][lrow] = wb.z;                                             \
    Bs[lseg * 4 + 3][lrow] = wb.w;                                             \
    __syncthreads();                                                           \
    _Pragma("unroll") for (int kk = 0; kk < 16; ++kk) {                        \
      float av[4], bv[4];                                                      \
      {                                                                        \
        const float4 t = *(const float4*)&As[kk][ty * 4];                      \
        av[0] = t.x; av[1] = t.y; av[2] = t.z; av[3] = t.w;                    \
      }                                                                        \
      {                                                                        \
        const float4 t = *(const float4*)&Bs[kk][tx * 4];                      \
        bv[0] = t.x; bv[1] = t.y; bv[2] = t.z; bv[3] = t.w;                    \
      }                                                                        \
      _Pragma("unroll") for (int i = 0; i < 4; ++i)                            \
      _Pragma("unroll") for (int j = 0; j < 4; ++j)                            \
        acc[i][j] += av[i] * bv[j];                                            \
    }                                                                          \
  }

// Projection for Q/K: out bf16 head-major [(b*8+h)*2048 + l][d], scaled.
__global__ __launch_bounds__(256) void gemm_qk_bf16(const float* __restrict__ X,
                                                    const float* __restrict__ W,
                                                    const float* __restrict__ bias,
                                                    unsigned short* __restrict__ out,
                                                    float scale) {
  GEMM_CORE(X, W)
  const int oc = n0 + tx * 4;
  const int hh = n0 >> 6;  // head (N tiles align with 64-wide heads)
#pragma unroll
  for (int i = 0; i < 4; ++i) {
    const int n = m0 + ty * 4 + i;
    const int bb = n >> 11, l = n & 2047;
    ushort4 o;
    o.x = f2bf((acc[i][0] + bias[oc + 0]) * scale);
    o.y = f2bf((acc[i][1] + bias[oc + 1]) * scale);
    o.z = f2bf((acc[i][2] + bias[oc + 2]) * scale);
    o.w = f2bf((acc[i][3] + bias[oc + 3]) * scale);
    *(ushort4*)&out[(((size_t)bb * NH + hh) * NL + l) * 64 + tx * 4] = o;
  }
}

// Projection for V: out bf16 TRANSPOSED per head: [(b*8+h)*64 + d][l].
__global__ __launch_bounds__(256) void gemm_v_bf16t(const float* __restrict__ X,
                                                    const float* __restrict__ W,
                                                    const float* __restrict__ bias,
                                                    unsigned short* __restrict__ outT) {
  GEMM_CORE(X, W)
  const int oc = n0 + tx * 4;
  const int hh = n0 >> 6;
  const int n_base = m0 + ty * 4;
  const int bb = n_base >> 11;
  const int l0 = n_base & 2047;
#pragma unroll
  for (int j = 0; j < 4; ++j) {
    const int d = tx * 4 + j;
    ushort4 o;
    o.x = f2bf(acc[0][j] + bias[oc + j]);
    o.y = f2bf(acc[1][j] + bias[oc + j]);
    o.z = f2bf(acc[2][j] + bias[oc + j]);
    o.w = f2bf(acc[3][j] + bias[oc + j]);
    *(ushort4*)&outT[(((size_t)bb * NH + hh) * 64 + d) * NL + l0] = o;
  }
}

// ---------------------------------------------------------------------------
// MFMA attention. Block = 4 waves; tile = 64 q x (b,h). Two passes:
//  P1: S = Q.K^T (mfma), mask (cached to VGPR bits), exp, rowsum.
//  P2: recompute S, p = exp(s)*inv, write attn, P->LDS(bf16), O += P.V (mfma).
// LDS rows padded to 72 bf16 (144 B, 16B-aligned, uniform banks).
// Fragment maps (m89/m91/m120-verified): A/B [nonK=lane&15][K=quad*8+j],
// C/D [row=quad*4+reg][col=lane&15].
// ---------------------------------------------------------------------------
__global__ __launch_bounds__(256) void attn_mfma(const unsigned short* __restrict__ qh,
                                                 const unsigned short* __restrict__ kh,
                                                 const unsigned short* __restrict__ vT,
                                                 const int* __restrict__ mask,
                                                 float* __restrict__ attn,
                                                 float* __restrict__ ao) {
  const int b = blockIdx.z, h = blockIdx.y, q0 = blockIdx.x * 64;
  const int bh = b * NH + h;
  __shared__ unsigned short Ks[64 * 72];
  __shared__ unsigned short Vt[64 * 72];
  __shared__ unsigned short Ps[4 * 16 * 72];  // per-wave 16x72 strips
  const int tid = threadIdx.x;
  const int w = tid >> 6, lane = tid & 63;
  const int quad = lane >> 4, l15 = lane & 15;

  // Q fragments (row = q0 + w*16 + l15), qh pre-scaled by 1/8
  const size_t qoff = ((size_t)bh * NL + q0 + w * 16 + l15) * 64 + quad * 8;
  const bf16x8 aq0 = *(const bf16x8*)(qh + qoff);
  const bf16x8 aq1 = *(const bf16x8*)(qh + qoff + 32);

  const int srow = tid >> 2;        // 0..63
  const int scol = (tid & 3) * 16;  // ushort offset {0,16,32,48}

  float rinv[4] = {0.f, 0.f, 0.f, 0.f};  // rowsum during P1, then 1/sum
  unsigned int mbits[16];
#pragma unroll
  for (int i = 0; i < 16; ++i) mbits[i] = 0;

  // ---------------- PASS 1 ----------------
  for (int kt = 0; kt < 32; ++kt) {
    const unsigned short* kg = kh + ((size_t)bh * NL + kt * 64 + srow) * 64 + scol;
    const uint4 k0 = *(const uint4*)kg;
    const uint4 k1 = *(const uint4*)(kg + 8);
    __syncthreads();
    *(uint4*)&Ks[srow * 72 + scol] = k0;
    *(uint4*)&Ks[srow * 72 + scol + 8] = k1;
    __syncthreads();
    f32x4 s[4];
#pragma unroll
    for (int nt = 0; nt < 4; ++nt) {
      const bf16x8 b0 = *(const bf16x8*)&Ks[(nt * 16 + l15) * 72 + quad * 8];
      const bf16x8 b1 = *(const bf16x8*)&Ks[(nt * 16 + l15) * 72 + 32 + quad * 8];
      f32x4 acc = {0.f, 0.f, 0.f, 0.f};
      acc = __builtin_amdgcn_mfma_f32_16x16x32_bf16(aq0, b0, acc, 0, 0, 0);
      acc = __builtin_amdgcn_mfma_f32_16x16x32_bf16(aq1, b1, acc, 0, 0, 0);
      s[nt] = acc;
    }
    unsigned int mb = 0;
#pragma unroll
    for (int r = 0; r < 4; ++r) {
      const size_t mrow = ((size_t)b * NL + q0 + w * 16 + quad * 4 + r) * NL + kt * 64;
#pragma unroll
      for (int nt = 0; nt < 4; ++nt) {
        const int mz = mask[mrow + nt * 16 + l15];
        float e = __expf(s[nt][r]);
        if (mz == 1) {
          mb |= (1u << (nt * 4 + r));
          e = 0.f;
        }
        rinv[r] += e;
      }
    }
    mbits[kt >> 1] |= mb << ((kt & 1) * 16);
  }
  // reduce rowsums across the 16 lanes of each quad; invert
#pragma unroll
  for (int r = 0; r < 4; ++r) {
    float v = rinv[r];
    v += __shfl_xor(v, 1);
    v += __shfl_xor(v, 2);
    v += __shfl_xor(v, 4);
    v += __shfl_xor(v, 8);
    rinv[r] = 1.0f / v;
  }

  // ---------------- PASS 2 ----------------
  f32x4 oacc[4];
#pragma unroll
  for (int nt = 0; nt < 4; ++nt) oacc[nt] = (f32x4){0.f, 0.f, 0.f, 0.f};

  for (int kt = 0; kt < 32; ++kt) {
    const unsigned short* kg = kh + ((size_t)bh * NL + kt * 64 + srow) * 64 + scol;
    const unsigned short* vg = vT + ((size_t)bh * 64 + srow) * NL + kt * 64 + scol;
    const uint4 k0 = *(const uint4*)kg;
    const uint4 k1 = *(const uint4*)(kg + 8);
    const uint4 v0 = *(const uint4*)vg;
    const uint4 v1 = *(const uint4*)(vg + 8);
    __syncthreads();
    *(uint4*)&Ks[srow * 72 + scol] = k0;
    *(uint4*)&Ks[srow * 72 + scol + 8] = k1;
    *(uint4*)&Vt[srow * 72 + scol] = v0;
    *(uint4*)&Vt[srow * 72 + scol + 8] = v1;
    __syncthreads();
    f32x4 s[4];
#pragma unroll
    for (int nt = 0; nt < 4; ++nt) {
      const bf16x8 b0 = *(const bf16x8*)&Ks[(nt * 16 + l15) * 72 + quad * 8];
      const bf16x8 b1 = *(const bf16x8*)&Ks[(nt * 16 + l15) * 72 + 32 + quad * 8];
      f32x4 acc = {0.f, 0.f, 0.f, 0.f};
      acc = __builtin_amdgcn_mfma_f32_16x16x32_bf16(aq0, b0, acc, 0, 0, 0);
      acc = __builtin_amdgcn_mfma_f32_16x16x32_bf16(aq1, b1, acc, 0, 0, 0);
      s[nt] = acc;
    }
    const unsigned int mb = mbits[kt >> 1] >> ((kt & 1) * 16);
#pragma unroll
    for (int r = 0; r < 4; ++r) {
      const int q = q0 + w * 16 + quad * 4 + r;
      float* arow = attn + ((size_t)bh * NL + q) * NL + kt * 64;
      unsigned short* prow = &Ps[(w * 16 + quad * 4 + r) * 72];
#pragma unroll
      for (int nt = 0; nt < 4; ++nt) {
        float e = ((mb >> (nt * 4 + r)) & 1u) ? 0.f : __expf(s[nt][r]) * rinv[r];
        arow[nt * 16 + l15] = e;
        prow[nt * 16 + l15] = f2bf(e);
      }
    }
    // PV: per-wave P strip (no barrier needed; same-wave LDS RAW)
    const bf16x8 pa0 = *(const bf16x8*)&Ps[(w * 16 + l15) * 72 + quad * 8];
    const bf16x8 pa1 = *(const bf16x8*)&Ps[(w * 16 + l15) * 72 + 32 + quad * 8];
#pragma unroll
    for (int nt = 0; nt < 4; ++nt) {
      const bf16x8 vb0 = *(const bf16x8*)&Vt[(nt * 16 + l15) * 72 + quad * 8];
      const bf16x8 vb1 = *(const bf16x8*)&Vt[(nt * 16 + l15) * 72 + 32 + quad * 8];
      oacc[nt] = __builtin_amdgcn_mfma_f32_16x16x32_bf16(pa0, vb0, oacc[nt], 0, 0, 0);
      oacc[nt] = __builtin_amdgcn_mfma_f32_16x16x32_bf16(pa1, vb1, oacc[nt], 0, 0, 0);
    }
  }
  // write attention-out (b,h,q,d) f32
#pragma unroll
  for (int r = 0; r < 4; ++r) {
    float* orow = ao + ((size_t)bh * NL + q0 + w * 16 + quad * 4 + r) * 64;
#pragma unroll
    for (int nt = 0; nt < 4; ++nt) orow[nt * 16 + l15] = oacc[nt][r];
  }
}

// ---------------------------------------------------------------------------
// fc with the faithful buffer-scramble gather on A + bias + residual.
// ---------------------------------------------------------------------------
__global__ __launch_bounds__(256) void fc_gather(const float* __restrict__ AO,
                                                 const float* __restrict__ W,
                                                 const float* __restrict__ bias,
                                                 const float* __restrict__ resid,
                                                 float* __restrict__ Xout) {
  __shared__ float As[16][64];
  __shared__ float Bs[16][64];
  const int tid = threadIdx.x;
  const int tx = tid & 15, ty = tid >> 4;
  const int m0 = blockIdx.x * 64, n0 = blockIdx.y * 64;
  const int lrow = tid >> 2, lseg = tid & 3;
  const int n = m0 + lrow;
  const int b_out = n >> 11;
  const int l_out = n & 2047;
  const int h2 = b_out * 2 + (l_out >> 10);
  const int q2base = (l_out & 1023) << 1;
  float acc[4][4] = {};
  for (int k0 = 0; k0 < 512; k0 += 16) {
    const int c = k0 + lseg * 4;
    const int q2 = q2base | ((c >> 8) & 1);
    const int b2 = (c >> 6) & 3;
    const int d2 = c & 63;
    const float4 xa = *(const float4*)&AO[((size_t)(h2 * 4 + b2) * NL + q2) * 64 + d2];
    const float4 wb = *(const float4*)&W[(size_t)(n0 + lrow) * ND + c];
    __syncthreads();
    As[lseg * 4 + 0][lrow] = xa.x;
    As[lseg * 4 + 1][lrow] = xa.y;
    As[lseg * 4 + 2][lrow] = xa.z;
    As[lseg * 4 + 3][lrow] = xa.w;
    Bs[lseg * 4 + 0][lrow] = wb.x;
    Bs[lseg * 4 + 1][lrow] = wb.y;
    Bs[lseg * 4 + 2][lrow] = wb.z;
    Bs[lseg * 4 + 3][lrow] = wb.w;
    __syncthreads();
#pragma unroll
    for (int kk = 0; kk < 16; ++kk) {
      float av[4], bv[4];
      {
        const float4 t = *(const float4*)&As[kk][ty * 4];
        av[0] = t.x; av[1] = t.y; av[2] = t.z; av[3] = t.w;
      }
      {
        const float4 t = *(const float4*)&Bs[kk][tx * 4];
        bv[0] = t.x; bv[1] = t.y; bv[2] = t.z; bv[3] = t.w;
      }
#pragma unroll
      for (int i = 0; i < 4; ++i)
#pragma unroll
        for (int j = 0; j < 4; ++j) acc[i][j] += av[i] * bv[j];
    }
  }
  const int oc = n0 + tx * 4;
#pragma unroll
  for (int i = 0; i < 4; ++i) {
    const float4 r = *(const float4*)&resid[(size_t)(m0 + ty * 4 + i) * ND + oc];
    float4 o;
    o.x = acc[i][0] + bias[oc + 0] + r.x;
    o.y = acc[i][1] + bias[oc + 1] + r.y;
    o.z = acc[i][2] + bias[oc + 2] + r.z;
    o.w = acc[i][3] + bias[oc + 3] + r.w;
    *(float4*)&Xout[(size_t)(m0 + ty * 4 + i) * ND + oc] = o;
  }
}

// ---------------------------------------------------------------------------
// LayerNorm over last dim (512), one wave per token.
// ---------------------------------------------------------------------------
__global__ __launch_bounds__(64) void layernorm_k(const float* __restrict__ x,
                                                  const float* __restrict__ g,
                                                  const float* __restrict__ bta,
                                                  float* __restrict__ y) {
  const int n = blockIdx.x;
  const int lane = threadIdx.x;
  const float* row = x + (size_t)n * ND;
  const float4 a = *(const float4*)&row[lane * 8];
  const float4 c = *(const float4*)&row[lane * 8 + 4];
  float s = a.x + a.y + a.z + a.w + c.x + c.y + c.z + c.w;
  float sq = a.x * a.x + a.y * a.y + a.z * a.z + a.w * a.w +
             c.x * c.x + c.y * c.y + c.z * c.z + c.w * c.w;
#pragma unroll
  for (int off = 32; off; off >>= 1) {
    s += __shfl_down(s, off);
    sq += __shfl_down(sq, off);
  }
  s = __shfl(s, 0);
  sq = __shfl(sq, 0);
  const float mu = s * (1.f / 512.f);
  const float var = sq * (1.f / 512.f) - mu * mu;
  const float rstd = rsqrtf(var + LN_EPS);
  float* yo = y + (size_t)n * ND;
  const int c0 = lane * 8;
  float4 o1, o2;
  o1.x = (a.x - mu) * rstd * g[c0 + 0] + bta[c0 + 0];
  o1.y = (a.y - mu) * rstd * g[c0 + 1] + bta[c0 + 1];
  o1.z = (a.z - mu) * rstd * g[c0 + 2] + bta[c0 + 2];
  o1.w = (a.w - mu) * rstd * g[c0 + 3] + bta[c0 + 3];
  o2.x = (c.x - mu) * rstd * g[c0 + 4] + bta[c0 + 4];
  o2.y = (c.y - mu) * rstd * g[c0 + 5] + bta[c0 + 5];
  o2.z = (c.z - mu) * rstd * g[c0 + 6] + bta[c0 + 6];
  o2.w = (c.w - mu) * rstd * g[c0 + 7] + bta[c0 + 7];
  *(float4*)&yo[c0] = o1;
  *(float4*)&yo[c0 + 4] = o2;
}

extern "C" void kernel_launch(void* const* d_in, const int* in_sizes, int n_in,
                              void* d_out, int out_size, void* d_ws, size_t ws_size,
                              hipStream_t stream) {
  const float* q = (const float*)d_in[0];
  const float* k = (const float*)d_in[1];
  const float* v = (const float*)d_in[2];
  const int* mask = (const int*)d_in[3];
  const float* wq_w = (const float*)d_in[4];
  const float* wq_b = (const float*)d_in[5];
  const float* wv_w = (const float*)d_in[6];
  const float* wv_b = (const float*)d_in[7];
  const float* fc_w = (const float*)d_in[8];
  const float* fc_b = (const float*)d_in[9];
  const float* ln_g = (const float*)d_in[10];
  const float* ln_b = (const float*)d_in[11];

  float* y = (float*)d_out;
  float* attn = y + (size_t)NTOK * ND;  // second output, (B,H,L,L)

  const size_t SZ = (size_t)NTOK * ND;  // 4,194,304 elements
  unsigned short* qhb = (unsigned short*)d_ws;       // bf16 head-major, scaled
  unsigned short* khb = qhb + SZ;                    // bf16 head-major
  unsigned short* vTb = khb + SZ;                    // bf16 per-head transposed
  float* ao = (float*)(vTb + SZ);                    // attention out f32 (b,h,q,d)
  float* xx = ao + SZ;                               // fc out + residual

  const dim3 gproj(NTOK / 64, ND / 64);  // 128 x 8
  gemm_qk_bf16<<<gproj, 256, 0, stream>>>(q, wq_w, wq_b, qhb, 0.125f);
  gemm_qk_bf16<<<gproj, 256, 0, stream>>>(k, wq_w, wq_b, khb, 1.0f);
  gemm_v_bf16t<<<gproj, 256, 0, stream>>>(v, wv_w, wv_b, vTb);
  attn_mfma<<<dim3(NL / 64, NH, NB), 256, 0, stream>>>(qhb, khb, vTb, mask, attn, ao);
  fc_gather<<<gproj, 256, 0, stream>>>(ao, fc_w, fc_b, q, xx);
  layernorm_k<<<NTOK, 64, 0, stream>>>(xx, ln_g, ln_b, y);
}